// Round 1
// 458.208 us; speedup vs baseline: 1.1443x; 1.1443x over previous
//
#include <hip/hip_runtime.h>
#include <cstdint>
#include <cstddef>

// Problem constants (from reference)
#define TOKENS 2048
#define IN_F   4096
#define OUT_F  11008
#define W_BIT  4
#define RANK   16
#define QWB    (OUT_F * IN_F / 8)   // 5,636,096 int32 "bytes" per bit-plane

typedef unsigned short ushort_t;
typedef __attribute__((ext_vector_type(8))) short   short8;   // 8 bf16 = 4 VGPRs (MFMA A/B frag)
typedef __attribute__((ext_vector_type(4))) float   floatx4;  // MFMA C/D frag

__device__ __forceinline__ ushort_t f2bf(float f) {
  union { float f; uint32_t u; } c; c.f = f;
  uint32_t r = c.u + 0x7FFFu + ((c.u >> 16) & 1u);  // RNE
  return (ushort_t)(r >> 16);
}

// async global->LDS, 16B per lane; lds pointer must be wave-uniform base (HW adds lane*16)
__device__ __forceinline__ void gl_lds16(const void* g, void* l) {
  __builtin_amdgcn_global_load_lds(
      (const __attribute__((address_space(1))) uint32_t*)g,
      (__attribute__((address_space(3))) uint32_t*)l, 16, 0, 0);
}

// ---------------- phase 0a: x fp32 -> bf16 ----------------
__global__ __launch_bounds__(256) void k_cvt_x(const float* __restrict__ x,
                                               ushort_t* __restrict__ xb) {
  int idx = blockIdx.x * 256 + threadIdx.x;
  float4 v = ((const float4*)x)[idx];
  ushort4 r;
  r.x = f2bf(v.x); r.y = f2bf(v.y); r.z = f2bf(v.z); r.w = f2bf(v.w);
  ((ushort4*)xb)[idx] = r;
}

// ---------------- phase 0b: u -> bf16 (same layout), vt -> bf16 transposed ----------------
#define N_U  (W_BIT * OUT_F * RANK)   // 704512
#define N_VT (W_BIT * RANK * IN_F)    // 262144
__global__ __launch_bounds__(256) void k_prep_uv(const float* __restrict__ u,
                                                 const float* __restrict__ vt,
                                                 ushort_t* __restrict__ ub,
                                                 ushort_t* __restrict__ vtT) {
  int idx = blockIdx.x * 256 + threadIdx.x;
  if (idx < N_U) {
    ub[idx] = f2bf(u[idx]);
  } else {
    int e = idx - N_U;                 // [0, N_VT)
    int b = e >> 16;                   // RANK*IN_F = 65536
    int r = e & 65535;
    int k = r >> 12;                   // IN_F = 4096
    int i = r & 4095;
    vtT[((size_t)b * IN_F + i) * RANK + k] = f2bf(vt[e]);
  }
}

// ---------------- phase 1: build w (bf16): MFMA product + LDS-staged sign apply ----
__global__ __launch_bounds__(256) void k_build_w(const int* __restrict__ qw,
                                                 const ushort_t* __restrict__ ub,
                                                 const ushort_t* __restrict__ vtT,
                                                 ushort_t* __restrict__ w) {
  __shared__ int qs[W_BIT * 128 * 20];  // 40 KB
  const int tid = threadIdx.x;
  const int ob = blockIdx.x / (IN_F / 128);
  const int ib = blockIdx.x % (IN_F / 128);
  const int o0 = ob * 128, i0 = ib * 128;
  const int lane = tid & 63, wv = tid >> 6;
  const int wm = (wv >> 1) * 64, wn = (wv & 1) * 64;
  const int l16 = lane & 15, q = lane >> 4;
  const bool qlo = (q < 2);
  const int koff = (q & 1) * 8;        // valid k-halves for q=0,1; q>=2 zeroed
  const short8 zf = (short8)0;

  // stage qw tile: 4 planes x 128 rows x 16 ints; 2048 int4 chunks, 8/thread, coalesced
  #pragma unroll
  for (int n = 0; n < 8; ++n) {
    int c = n * 256 + tid;             // [0, 2048)
    int b = c >> 9, rem = c & 511;
    int row = rem >> 2, part = rem & 3;
    int4 v = *(const int4*)(qw + (size_t)b * QWB +
                            (size_t)(o0 + row) * (IN_F / 8) + (i0 >> 3) + part * 4);
    *(int4*)&qs[(b * 128 + row) * 20 + part * 4] = v;
  }

  floatx4 acc[16];
  #pragma unroll
  for (int i = 0; i < 16; ++i) acc[i] = (floatx4){0.f, 0.f, 0.f, 0.f};

  const int qc_base = (wn >> 3) + (l16 >> 3);  // LDS int col for this lane (+ni*2)
  const int bit = l16 & 7;

  __syncthreads();

  #pragma unroll
  for (int b = 0; b < W_BIT; ++b) {
    short8 af[4], bfr[4];
    #pragma unroll
    for (int mi = 0; mi < 4; ++mi) {
      short8 v = *(const short8*)&ub[((size_t)b * OUT_F + o0 + wm + mi * 16 + l16) * RANK + koff];
      af[mi] = qlo ? v : zf;
    }
    #pragma unroll
    for (int ni = 0; ni < 4; ++ni) {
      short8 v = *(const short8*)&vtT[((size_t)b * IN_F + i0 + wn + ni * 16 + l16) * RANK + koff];
      bfr[ni] = qlo ? v : zf;
    }

    #pragma unroll
    for (int mi = 0; mi < 4; ++mi) {
      floatx4 p[4];
      #pragma unroll
      for (int ni = 0; ni < 4; ++ni)
        p[ni] = __builtin_amdgcn_mfma_f32_16x16x32_bf16(
            af[mi], bfr[ni], (floatx4){0.f, 0.f, 0.f, 0.f}, 0, 0, 0);
      // C layout: col = l16, row = q*4 + v4  [verified m89/m91]
      #pragma unroll
      for (int v4 = 0; v4 < 4; ++v4) {
        const int o_loc = wm + mi * 16 + q * 4 + v4;
        const int* qrow = &qs[(b * 128 + o_loc) * 20];
        #pragma unroll
        for (int ni = 0; ni < 4; ++ni) {
          int qv = qrow[qc_base + ni * 2];
          float pv = p[ni][v4];
          acc[mi * 4 + ni][v4] += ((qv >> bit) & 1) ? pv : -pv;
        }
      }
    }
  }

  #pragma unroll
  for (int mi = 0; mi < 4; ++mi) {
    #pragma unroll
    for (int v4 = 0; v4 < 4; ++v4) {
      const int o = o0 + wm + mi * 16 + q * 4 + v4;
      #pragma unroll
      for (int ni = 0; ni < 4; ++ni)
        w[(size_t)o * IN_F + i0 + wn + ni * 16 + l16] = f2bf(acc[mi * 4 + ni][v4]);
    }
  }
}

// ---------------- phase 2: y = x @ w^T  (bf16 MFMA gemm_bt, deep-pipelined) ----------------
// M=2048, N=11008, K=4096. BM=128, BN=256, BK=32. 512 threads = 8 waves (2Mx4N),
// wave tile 64x64 = 4x4 frags of 16x16x32.
//
// Structure (T3+T4 counted-vmcnt ring, provably race-free):
//  - 4-slot LDS ring (A 4x8KB + B 4x16KB = 96KB), staging depth 3 K-tiles.
//  - per tile: raw s_barrier -> issue STAGE(t+3) -> s_waitcnt vmcnt(6) (never 0 in
//    steady state; tiles t+2,t+3 = 6 loads stay in flight ACROSS the barrier)
//    -> s_barrier -> ds_read frags of tile t+1 -> 16 MFMA on tile t's registers.
//    Slot (t+3)&3 is free: tile t-1's ds_reads were forced complete by its MFMAs
//    (register dep) before the top barrier.
//  - register frag double-buffer (a0/b0 vs a1/b1, static names per rule #20):
//    MFMAs never wait on the current tile's LDS latency.
//  - T2 bank swizzle: chunk' = chunk ^ ((row>>1)&3) on 16B chunks of each 64B row.
//    16 l16-lanes -> 8 distinct 4-bank groups x2 = 2-way (free). global_load_lds dest
//    stays linear; the INVERSE swizzle is applied to the per-lane global source addr
//    (rule #21). Both read- and stage-side terms are thread constants (zero loop VALU).
//  - T1 bijective XCD swizzle: grid 688 = 8*86.
#define NT (IN_F / 32)   // 128 K-tiles
__global__ __launch_bounds__(512) void k_gemm_bt(const ushort_t* __restrict__ A,  // [2048][4096]
                                                 const ushort_t* __restrict__ B,  // [11008][4096]
                                                 float* __restrict__ C) {         // [2048][11008]
  __shared__ __attribute__((aligned(16))) char lds[98304];  // A: 4x8KB @0 | B: 4x16KB @32KB
  const int tid = threadIdx.x;
  const int wg = (blockIdx.x & 7) * 86 + (blockIdx.x >> 3);  // bijective XCD swizzle
  const int bm = wg & 15;    // 16 M-tiles of 128
  const int bn = wg >> 4;    // 43 N-tiles of 256
  const int lane = tid & 63, wv = tid >> 6;
  const int wm = wv >> 2, wn = wv & 3;      // wave grid 2(M) x 4(N), wave tile 64x64
  const int l16 = lane & 15, q = lane >> 4;
  const int sQ = q ^ ((l16 >> 1) & 3);      // read-side swizzled 16B-chunk slot (thread const)

  const size_t ar = (size_t)bm * 128, br = (size_t)bn * 256;
  // staging: A-tile 128x32 = 512 chunks (1/thread); B-tile 256x32 = 1024 chunks (2/thread)
  // chunk c: row = c>>2, slot = c&3, source k-chunk = slot ^ ((row>>1)&3)  (inverse swizzle)
  const int qsrc = (tid & 3) ^ ((tid >> 3) & 3);            // same for A, B-i0, B-i1
  const ushort_t* Ae  = A + (ar + (tid >> 2)) * IN_F + qsrc * 8;
  const ushort_t* B0e = B + (br + (tid >> 2)) * IN_F + qsrc * 8;
  const ushort_t* B1e = B + (br + 128 + (tid >> 2)) * IN_F + qsrc * 8;
  char* ldsw = lds + (tid & 448) * 16;      // wave-uniform dest base (HW adds lane*16)
  const int aFrag = (wm * 64 + l16) * 64 + sQ * 16;   // byte offset within A slot (+mi*1024)
  const int bFrag = (wn * 64 + l16) * 64 + sQ * 16;   // byte offset within B slot (+ni*1024)

  floatx4 acc[4][4];
  #pragma unroll
  for (int mi = 0; mi < 4; ++mi)
    #pragma unroll
    for (int ni = 0; ni < 4; ++ni) acc[mi][ni] = (floatx4){0.f, 0.f, 0.f, 0.f};

  short8 a0[4], b0[4], a1[4], b1[4];

#define STAGE(tt) do {                                                       \
    const int _sl = (tt) & 3; const size_t _k0 = (size_t)(tt) * 32;          \
    gl_lds16(Ae + _k0,  ldsw + _sl * 8192);                                  \
    gl_lds16(B0e + _k0, ldsw + 32768 + _sl * 16384);                         \
    gl_lds16(B1e + _k0, ldsw + 32768 + _sl * 16384 + 8192);                  \
  } while (0)

#define LDFRAGS(AF, BF, sl) do {                                             \
    const char* _ab = lds + (sl) * 8192;                                     \
    const char* _bb = lds + 32768 + (sl) * 16384;                            \
    _Pragma("unroll") for (int mi = 0; mi < 4; ++mi)                         \
      AF[mi] = *(const short8*)(_ab + aFrag + mi * 1024);                    \
    _Pragma("unroll") for (int ni = 0; ni < 4; ++ni)                         \
      BF[ni] = *(const short8*)(_bb + bFrag + ni * 1024);                    \
  } while (0)

#define BODY(u, AI, BI, AM, BMr) do {                                        \
    asm volatile("" ::: "memory");                                           \
    __builtin_amdgcn_s_barrier();        /* closes frag-reads of tile u-1 */ \
    asm volatile("" ::: "memory");                                           \
    if ((u) + 3 < NT) STAGE((u) + 3);    /* into slot just freed */          \
    if ((u) + 3 < NT)      asm volatile("s_waitcnt vmcnt(6)" ::: "memory");  \
    else if ((u) + 2 < NT) asm volatile("s_waitcnt vmcnt(3)" ::: "memory");  \
    else                   asm volatile("s_waitcnt vmcnt(0)" ::: "memory");  \
    __builtin_amdgcn_s_barrier();        /* publish tile u+1 residency */    \
    asm volatile("" ::: "memory");                                           \
    LDFRAGS(AI, BI, ((u) + 1) & 3);      /* prefetch frags of tile u+1 */    \
    __builtin_amdgcn_s_setprio(1);                                           \
    _Pragma("unroll") for (int mi = 0; mi < 4; ++mi)                         \
      _Pragma("unroll") for (int ni = 0; ni < 4; ++ni)                       \
        acc[mi][ni] = __builtin_amdgcn_mfma_f32_16x16x32_bf16(               \
            AM[mi], BMr[ni], acc[mi][ni], 0, 0, 0);                          \
    __builtin_amdgcn_s_setprio(0);                                           \
  } while (0)

  // prologue: stage tiles 0..2 (9 loads out), wait tile 0 (allow 6), read its frags
  STAGE(0); STAGE(1); STAGE(2);
  asm volatile("s_waitcnt vmcnt(6)" ::: "memory");
  __builtin_amdgcn_s_barrier();
  asm volatile("" ::: "memory");
  LDFRAGS(a0, b0, 0);

  for (int t = 0; t < NT; t += 2) {
    BODY(t,     a1, b1, a0, b0);
    BODY(t + 1, a0, b0, a1, b1);
  }

#undef STAGE
#undef LDFRAGS
#undef BODY

  // C/D layout: col = lane&15, row = (lane>>4)*4 + reg  [verified m89/m91]
  #pragma unroll
  for (int mi = 0; mi < 4; ++mi) {
    #pragma unroll
    for (int ni = 0; ni < 4; ++ni) {
      #pragma unroll
      for (int v = 0; v < 4; ++v) {
        int r = bm * 128 + wm * 64 + mi * 16 + q * 4 + v;
        int c = bn * 256 + wn * 64 + ni * 16 + l16;
        C[(size_t)r * OUT_F + c] = acc[mi][ni][v];
      }
    }
  }
}

extern "C" void kernel_launch(void* const* d_in, const int* in_sizes, int n_in,
                              void* d_out, int out_size, void* d_ws, size_t ws_size,
                              hipStream_t stream) {
  (void)in_sizes; (void)n_in; (void)out_size; (void)ws_size;
  const float* x  = (const float*)d_in[0];
  const int*   qw = (const int*)d_in[1];
  const float* u  = (const float*)d_in[2];
  const float* vt = (const float*)d_in[3];
  float* out = (float*)d_out;

  // workspace layout (bytes):
  //   xb  @ 0         : 2048*4096*2   = 16,777,216
  //   wb  @ 16.0 MB   : 11008*4096*2  = 90,177,536
  //   ub  @ 102.0 MB  : 4*11008*16*2  = 1,409,024
  //   vtT @ 103.3 MB  : 4*4096*16*2   = 524,288     (total ~103.8 MiB)
  char* wsp = (char*)d_ws;
  ushort_t* xb  = (ushort_t*)wsp;
  ushort_t* wb  = (ushort_t*)(wsp + (size_t)TOKENS * IN_F * 2);
  ushort_t* ubf = (ushort_t*)(wsp + (size_t)TOKENS * IN_F * 2 + (size_t)OUT_F * IN_F * 2);
  ushort_t* vtT = (ushort_t*)(wsp + (size_t)TOKENS * IN_F * 2 + (size_t)OUT_F * IN_F * 2 +
                              (size_t)N_U * 2);

  k_cvt_x<<<TOKENS * IN_F / 1024, 256, 0, stream>>>(x, xb);
  k_prep_uv<<<(N_U + N_VT) / 256, 256, 0, stream>>>(u, vt, ubf, vtT);
  k_build_w<<<(OUT_F / 128) * (IN_F / 128), 256, 0, stream>>>(qw, ubf, vtT, wb);
  k_gemm_bt<<<16 * (OUT_F / 256), 512, 0, stream>>>(xb, wb, out);
}